// Round 1
// baseline (325.725 us; speedup 1.0000x reference)
//
#include <hip/hip_runtime.h>

// SpeakerCrossAttention on MI355X (gfx950)
// B=16, D=512, T=8192, S=256. All inputs/outputs f32; big GEMM done in bf16 MFMA.
//
// Pipeline:
//  prep_kernel: blocks 0..15  -> per-batch chain: normalize spk, 3 GEMVs, LayerNorm,
//                                bias_b = attn_n @ W1a^T + bg1   (all f32, to d_ws)
//               blocks 16..143-> convert W1f = Wg1[:, :512] to bf16 row-major (d_ws)
//  main_kernel: 2048 blocks (16 b x 128 t-tiles of 64), 512 thr (8 waves):
//     stage features[b, :, t0:t0+64] -> LDS bf16 [t][k] (stride 520)
//     GEMM h^T = W1f * F^T via mfma_f32_16x16x32_bf16, wave = 64n x 64t, no K-loop barriers
//     alpha[t] = sigmoid(sum_n relu(h+bias)*Wg2 + bg2) via in-reg + shfl + LDS reduce
//     out[b,n,t] = alpha[t]*f + (1-alpha[t])*attn_n[b,n]  (reads bf16 tile from LDS)

typedef __attribute__((ext_vector_type(8))) short  short8;   // 8 bf16 = 4 VGPR (MFMA A/B frag)
typedef __attribute__((ext_vector_type(4))) unsigned short ushort4v;
typedef __attribute__((ext_vector_type(4))) float  f32x4;

#define T_DIM 8192
#define D_DIM 512
#define KST   520   // LDS row stride (elems); 1040 B = 65*16 -> 16B-aligned rows, 4-bank shift

__device__ __forceinline__ unsigned short f2bf(float x) {  // RTNE f32 -> bf16
  unsigned u = __builtin_bit_cast(unsigned, x);
  u = (u + 0x7fffu + ((u >> 16) & 1u)) >> 16;
  return (unsigned short)u;
}
__device__ __forceinline__ float bf2f(unsigned short h) {
  return __builtin_bit_cast(float, ((unsigned)h) << 16);
}

// ---------------- prep kernel ----------------
__global__ __launch_bounds__(512) void prep_kernel(
    const float* __restrict__ spk_in, const float* __restrict__ Wsp,
    const float* __restrict__ bsp,    const float* __restrict__ Wv,
    const float* __restrict__ bv,     const float* __restrict__ Wo,
    const float* __restrict__ bo,     const float* __restrict__ gma,
    const float* __restrict__ bta,    const float* __restrict__ Wg1,
    const float* __restrict__ bg1,
    float* __restrict__ attnn, float* __restrict__ biasb,
    unsigned short* __restrict__ w1fx)
{
  int tid = threadIdx.x;
  int blk = blockIdx.x;

  if (blk >= 16) {                    // ---- W1f -> bf16 conversion ----
    int base = (blk - 16) * 2048 + tid;
    #pragma unroll
    for (int i = 0; i < 4; ++i) {
      int idx = base + i * 512;       // 128 blocks * 512 thr * 4 = 262144 = 512*512
      int n = idx >> 9, k = idx & 511;
      w1fx[idx] = f2bf(Wg1[n * 1024 + k]);
    }
    return;
  }

  // ---- per-batch chain ----
  int b = blk;
  __shared__ __attribute__((aligned(16))) float s_spk[256];
  __shared__ __attribute__((aligned(16))) float s_x[512];
  __shared__ __attribute__((aligned(16))) float s_y[512];
  __shared__ float red[512];

  float se = (tid < 256) ? spk_in[b * 256 + tid] : 0.f;
  red[tid] = se * se;
  __syncthreads();
  for (int s = 256; s > 0; s >>= 1) {
    if (tid < s) red[tid] += red[tid + s];
    __syncthreads();
  }
  float scale = 1.f / fmaxf(sqrtf(red[0]), 1e-12f);
  if (tid < 256) s_spk[tid] = se * scale;
  __syncthreads();

  // speaker_feat = spk @ Wsp^T + bsp
  {
    const float* wr = Wsp + (size_t)tid * 256;
    f32x4 a4 = {0.f, 0.f, 0.f, 0.f};
    #pragma unroll 8
    for (int s2 = 0; s2 < 256; s2 += 4)
      a4 += (*(const f32x4*)(wr + s2)) * (*(const f32x4*)(s_spk + s2));
    s_x[tid] = a4[0] + a4[1] + a4[2] + a4[3] + bsp[tid];
  }
  __syncthreads();

  // v = sf @ Wv^T + bv
  {
    const float* wr = Wv + (size_t)tid * 512;
    f32x4 a4 = {0.f, 0.f, 0.f, 0.f};
    #pragma unroll 8
    for (int s2 = 0; s2 < 512; s2 += 4)
      a4 += (*(const f32x4*)(wr + s2)) * (*(const f32x4*)(s_x + s2));
    s_y[tid] = a4[0] + a4[1] + a4[2] + a4[3] + bv[tid];
  }
  __syncthreads();

  // attn = v @ Wo^T + bo
  float attnv;
  {
    const float* wr = Wo + (size_t)tid * 512;
    f32x4 a4 = {0.f, 0.f, 0.f, 0.f};
    #pragma unroll 8
    for (int s2 = 0; s2 < 512; s2 += 4)
      a4 += (*(const f32x4*)(wr + s2)) * (*(const f32x4*)(s_y + s2));
    attnv = a4[0] + a4[1] + a4[2] + a4[3] + bo[tid];
  }

  // LayerNorm over D=512
  red[tid] = attnv;
  __syncthreads();
  for (int s = 256; s > 0; s >>= 1) {
    if (tid < s) red[tid] += red[tid + s];
    __syncthreads();
  }
  float mu = red[0] * (1.f / 512.f);
  __syncthreads();
  float dv = attnv - mu;
  red[tid] = dv * dv;
  __syncthreads();
  for (int s = 256; s > 0; s >>= 1) {
    if (tid < s) red[tid] += red[tid + s];
    __syncthreads();
  }
  float var = red[0] * (1.f / 512.f);
  float an = dv * rsqrtf(var + 1e-5f) * gma[tid] + bta[tid];
  s_x[tid] = an;                       // attn_n in s_x
  attnn[b * 512 + tid] = an;
  __syncthreads();

  // bias_b = attn_n @ W1a^T + bg1   (W1a = Wg1[:, 512:])
  {
    const float* wr = Wg1 + (size_t)tid * 1024 + 512;
    f32x4 a4 = {0.f, 0.f, 0.f, 0.f};
    #pragma unroll 8
    for (int s2 = 0; s2 < 512; s2 += 4)
      a4 += (*(const f32x4*)(wr + s2)) * (*(const f32x4*)(s_x + s2));
    biasb[b * 512 + tid] = a4[0] + a4[1] + a4[2] + a4[3] + bg1[tid];
  }
}

// ---------------- main kernel ----------------
__global__ __launch_bounds__(512, 4) void main_kernel(
    const float* __restrict__ feat, const unsigned short* __restrict__ w1fx,
    const float* __restrict__ attnn, const float* __restrict__ biasb,
    const float* __restrict__ wg2p,  const float* __restrict__ bg2p,
    float* __restrict__ out)
{
  __shared__ __attribute__((aligned(16))) unsigned short S[64 * KST];  // 66560 B
  __shared__ __attribute__((aligned(16))) float s_attn[512];
  __shared__ __attribute__((aligned(16))) float s_bias[512];
  __shared__ __attribute__((aligned(16))) float s_wg2[512];
  __shared__ float s_gpart[8 * 64];
  __shared__ float s_alpha[64];

  int tid = threadIdx.x;
  int b  = blockIdx.x >> 7;
  int t0 = (blockIdx.x & 127) << 6;
  const float* fb = feat + ((size_t)b * D_DIM) * T_DIM + t0;

  // ---- stage features tile (64 t x 512 k) -> bf16 LDS [t][k] ----
  {
    int mt = tid & 15;          // t-chunk (4 t each)
    int mk = tid >> 4;          // k-chunk (4 k each), 0..31 per iter
    int tt = mt * 4;
    #pragma unroll
    for (int it = 0; it < 4; ++it) {
      int k0 = (mk + it * 32) * 4;
      f32x4 r0 = *(const f32x4*)(fb + (size_t)(k0 + 0) * T_DIM + tt);
      f32x4 r1 = *(const f32x4*)(fb + (size_t)(k0 + 1) * T_DIM + tt);
      f32x4 r2 = *(const f32x4*)(fb + (size_t)(k0 + 2) * T_DIM + tt);
      f32x4 r3 = *(const f32x4*)(fb + (size_t)(k0 + 3) * T_DIM + tt);
      #pragma unroll
      for (int i = 0; i < 4; ++i) {
        ushort4v wv;
        wv[0] = f2bf(r0[i]); wv[1] = f2bf(r1[i]);
        wv[2] = f2bf(r2[i]); wv[3] = f2bf(r3[i]);
        *(ushort4v*)(&S[(tt + i) * KST + k0]) = wv;   // ds_write_b64, transposed store
      }
    }
    s_attn[tid] = attnn[b * 512 + tid];
    s_bias[tid] = biasb[b * 512 + tid];
    s_wg2[tid]  = wg2p[tid];
  }
  __syncthreads();

  // ---- GEMM: h^T = W1f * F^T ; wave w owns n in [64w,64w+64), all 64 t ----
  int l = tid & 63, w = tid >> 6;
  int g = l >> 4, c = l & 15;
  int n0w = w * 64;

  f32x4 acc[4][4];
  #pragma unroll
  for (int i = 0; i < 4; ++i)
    #pragma unroll
    for (int j = 0; j < 4; ++j)
      acc[i][j] = (f32x4){0.f, 0.f, 0.f, 0.f};

  const unsigned short* ap0 = w1fx + (size_t)(n0w + c) * 512 + g * 8;  // A: W1f rows
  const unsigned short* bp0 = &S[c * KST + g * 8];                     // B: features

  #pragma unroll 2
  for (int kk = 0; kk < 16; ++kk) {
    short8 af[4], bf[4];
    #pragma unroll
    for (int ni = 0; ni < 4; ++ni)
      af[ni] = *(const short8*)(ap0 + ni * (16 * 512) + kk * 32);
    #pragma unroll
    for (int tg = 0; tg < 4; ++tg)
      bf[tg] = *(const short8*)(bp0 + tg * (16 * KST) + kk * 32);     // ds_read_b128
    #pragma unroll
    for (int ni = 0; ni < 4; ++ni)
      #pragma unroll
      for (int tg = 0; tg < 4; ++tg)
        acc[ni][tg] = __builtin_amdgcn_mfma_f32_16x16x32_bf16(
            af[ni], bf[tg], acc[ni][tg], 0, 0, 0);
  }
  // lane l, reg r of acc[ni][tg]: h[n = n0w+16ni+4g+r][t = 16tg+c]

  // ---- alpha: g[t] = sum_n relu(h+bias)*wg2 ----
  float p0 = 0.f, p1 = 0.f, p2 = 0.f, p3 = 0.f;
  #pragma unroll
  for (int ni = 0; ni < 4; ++ni) {
    #pragma unroll
    for (int r = 0; r < 4; ++r) {
      int n = n0w + 16 * ni + 4 * g + r;
      float bb = s_bias[n], ww = s_wg2[n];
      p0 += fmaxf(acc[ni][0][r] + bb, 0.f) * ww;
      p1 += fmaxf(acc[ni][1][r] + bb, 0.f) * ww;
      p2 += fmaxf(acc[ni][2][r] + bb, 0.f) * ww;
      p3 += fmaxf(acc[ni][3][r] + bb, 0.f) * ww;
    }
  }
  p0 += __shfl_xor(p0, 16); p0 += __shfl_xor(p0, 32);
  p1 += __shfl_xor(p1, 16); p1 += __shfl_xor(p1, 32);
  p2 += __shfl_xor(p2, 16); p2 += __shfl_xor(p2, 32);
  p3 += __shfl_xor(p3, 16); p3 += __shfl_xor(p3, 32);
  if (l < 16) {
    s_gpart[w * 64 +  0 + l] = p0;
    s_gpart[w * 64 + 16 + l] = p1;
    s_gpart[w * 64 + 32 + l] = p2;
    s_gpart[w * 64 + 48 + l] = p3;
  }
  __syncthreads();
  if (tid < 64) {
    float gs = bg2p[0];
    #pragma unroll
    for (int w2 = 0; w2 < 8; ++w2) gs += s_gpart[w2 * 64 + tid];
    s_alpha[tid] = 1.f / (1.f + expf(-gs));
  }
  __syncthreads();

  // ---- blend + store: out[b,n,t0+t] = a*f + (1-a)*attn_n[n] ----
  {
    int tl = tid & 63, gg = tid >> 6;
    float al = s_alpha[tl], om = 1.f - al;
    float* ob = out + ((size_t)b * D_DIM) * T_DIM + t0 + tl;
    const unsigned short* srow = &S[tl * KST];
    #pragma unroll 4
    for (int it = 0; it < 16; ++it) {
      int n0 = it * 32 + gg * 4;
      ushort4v fv = *(const ushort4v*)(srow + n0);       // 4 consecutive k (=n)
      f32x4 an = *(const f32x4*)(&s_attn[n0]);
      #pragma unroll
      for (int i = 0; i < 4; ++i)
        ob[(size_t)(n0 + i) * T_DIM] = al * bf2f(fv[i]) + om * an[i];
    }
  }
}

extern "C" void kernel_launch(void* const* d_in, const int* in_sizes, int n_in,
                              void* d_out, int out_size, void* d_ws, size_t ws_size,
                              hipStream_t stream) {
  const float* features = (const float*)d_in[0];
  const float* spk      = (const float*)d_in[1];
  const float* Wsp      = (const float*)d_in[2];
  const float* bsp      = (const float*)d_in[3];
  const float* Wv       = (const float*)d_in[4];
  const float* bv       = (const float*)d_in[5];
  const float* Wo       = (const float*)d_in[6];
  const float* bo       = (const float*)d_in[7];
  const float* gma      = (const float*)d_in[8];
  const float* bta      = (const float*)d_in[9];
  const float* Wg1      = (const float*)d_in[10];
  const float* bg1      = (const float*)d_in[11];
  const float* Wg2      = (const float*)d_in[12];
  const float* bg2      = (const float*)d_in[13];
  float* out = (float*)d_out;

  // workspace: attn_n (16x512 f32) | bias_b (16x512 f32) | W1f bf16 (512x512) = 576 KB
  float* attnn = (float*)d_ws;
  float* biasb = attnn + 16 * 512;
  unsigned short* w1fx = (unsigned short*)(biasb + 16 * 512);

  prep_kernel<<<144, 512, 0, stream>>>(spk, Wsp, bsp, Wv, bv, Wo, bo, gma, bta,
                                       Wg1, bg1, attnn, biasb, w1fx);
  main_kernel<<<2048, 512, 0, stream>>>(features, w1fx, attnn, biasb, Wg2, bg2, out);
}